// Round 1
// baseline (3079.214 us; speedup 1.0000x reference)
//
#include <hip/hip_runtime.h>
#include <hip/hip_bf16.h>

// Sizes (fixed by the problem)
#define T_STEPS 16
#define BATCH   512
#define N_IN    3072
#define S1      256
#define S2      256
#define S3      128
#define NEXP    8
#define M_ROWS  (T_STEPS * BATCH)   // 8192

// ---------------------------------------------------------------------------
// Batched per-expert GEMM, fp32 data, fp64 accumulation.
// H[e][m][n] = sum_i A[m][i] * W[e][n][i]
// A: (M_ROWS x K) row-major fp32. W: (E x N x K) row-major fp32.
// grid: (M_ROWS/64, N/64, E), block: 256 threads.
// ---------------------------------------------------------------------------
template<int K, int N>
__global__ __launch_bounds__(256) void expert_gemm_f64(
    const float* __restrict__ A, const float* __restrict__ W,
    double* __restrict__ H)
{
    constexpr int BM = 64, BN = 64, BK = 32;
    // +1 pad (odd stride) -> compute-phase LDS reads are <=2-way (free on CDNA4)
    __shared__ float As[BM][BK + 1];
    __shared__ float Bs[BN][BK + 1];

    const int e  = blockIdx.z;
    const int m0 = blockIdx.x * BM;
    const int n0 = blockIdx.y * BN;
    const int tid = threadIdx.x;
    const int tx = tid & 15;   // n subtile
    const int ty = tid >> 4;   // m subtile

    const float* Ab = A + (size_t)m0 * K;
    const float* Wb = W + ((size_t)e * N + n0) * K;

    double acc[4][4];
    #pragma unroll
    for (int i = 0; i < 4; ++i)
        #pragma unroll
        for (int j = 0; j < 4; ++j) acc[i][j] = 0.0;

    for (int k0 = 0; k0 < K; k0 += BK) {
        // cooperative staging: 64 rows x 32 cols each for A and W
        #pragma unroll
        for (int i = 0; i < 8; ++i) {
            int li = tid + i * 256;   // 0..2047
            int r  = li >> 5;
            int c  = li & 31;
            As[r][c] = Ab[(size_t)r * K + k0 + c];
            Bs[r][c] = Wb[(size_t)r * K + k0 + c];
        }
        __syncthreads();

        #pragma unroll
        for (int kk = 0; kk < BK; ++kk) {
            double a[4], b[4];
            #pragma unroll
            for (int i = 0; i < 4; ++i) a[i] = (double)As[ty * 4 + i][kk];
            #pragma unroll
            for (int j = 0; j < 4; ++j) b[j] = (double)Bs[tx * 4 + j][kk];
            #pragma unroll
            for (int i = 0; i < 4; ++i)
                #pragma unroll
                for (int j = 0; j < 4; ++j)
                    acc[i][j] += a[i] * b[j];
        }
        __syncthreads();
    }

    double* Hb = H + ((size_t)e * M_ROWS + m0) * N + n0;
    #pragma unroll
    for (int i = 0; i < 4; ++i)
        #pragma unroll
        for (int j = 0; j < 4; ++j)
            Hb[(size_t)(ty * 4 + i) * N + (tx * 4 + j)] = acc[i][j];
}

// ---------------------------------------------------------------------------
// LIF scan + gated combine + running time-mean.
// One thread per (b, o). Keeps all 8 expert membrane potentials in registers,
// scans t = 0..15 sequentially (the only true sequential dependence).
// H: [E][T*B][S] fp64.  C: [T*B][S] fp32 (exact multiples of 1/8).
// Mean: [B][S] fp32 (exact multiples of 1/128).
// ---------------------------------------------------------------------------
template<int S>
__global__ __launch_bounds__(256) void lif_scan(
    const double* __restrict__ H, const float* __restrict__ g,
    float* __restrict__ C, float* __restrict__ Mean)
{
    const int idx = blockIdx.x * 256 + threadIdx.x;   // = b*S + o

    double v[NEXP];
    float  gv[NEXP];
    #pragma unroll
    for (int e = 0; e < NEXP; ++e) { v[e] = 0.0; gv[e] = g[e]; }

    float acc = 0.0f;
    for (int t = 0; t < T_STEPS; ++t) {
        float cs = 0.0f;
        #pragma unroll
        for (int e = 0; e < NEXP; ++e) {
            double h  = H[((size_t)e * M_ROWS + t * BATCH) * S + idx];
            double vv = v[e] * 0.95 + h;
            if (vv >= 1.0) { vv -= 1.0; cs += gv[e]; }
            v[e] = vv;
        }
        C[(size_t)t * BATCH * S + idx] = cs;
        acc += cs;
    }
    Mean[idx] = acc * 0.0625f;
}

// ---------------------------------------------------------------------------
// Launch: 3x (batched GEMM over all timesteps) + 3x LIF scan.
// ws layout: h (fp64, 134217728 B, reused per stage) | c1 (8 MB) | c2 (8 MB)
// ---------------------------------------------------------------------------
extern "C" void kernel_launch(void* const* d_in, const int* in_sizes, int n_in,
                              void* d_out, int out_size, void* d_ws, size_t ws_size,
                              hipStream_t stream) {
    const float* x  = (const float*)d_in[0];   // (T, B, N_IN)
    const float* W1 = (const float*)d_in[1];   // (E, S1, N_IN)
    const float* W2 = (const float*)d_in[2];   // (E, S2, S1)
    const float* W3 = (const float*)d_in[3];   // (E, S3, S2)
    const float* g1 = (const float*)d_in[4];
    const float* g2 = (const float*)d_in[5];
    const float* g3 = (const float*)d_in[6];
    float* out = (float*)d_out;

    char* ws = (char*)d_ws;
    double* h  = (double*)ws;                          // 8*8192*256*8 = 134217728 B max
    float*  c1 = (float*)(ws + 134217728ull);          // 16*512*256*4 = 8388608 B
    float*  c2 = (float*)(ws + 142606336ull);          // 8388608 B

    dim3 blk(256);

    // Stage 1: h1[e][t*B+b][o] = sum_i x[t][b][i] * W1[e][o][i]
    expert_gemm_f64<N_IN, S1><<<dim3(M_ROWS / 64, S1 / 64, NEXP), blk, 0, stream>>>(x, W1, h);
    lif_scan<S1><<<(BATCH * S1) / 256, blk, 0, stream>>>(h, g1, c1, out);

    // Stage 2
    expert_gemm_f64<S1, S2><<<dim3(M_ROWS / 64, S2 / 64, NEXP), blk, 0, stream>>>(c1, W2, h);
    lif_scan<S2><<<(BATCH * S2) / 256, blk, 0, stream>>>(h, g2, c2, out + BATCH * S1);

    // Stage 3 (c1 buffer reused as scratch for c3, which nothing consumes)
    expert_gemm_f64<S2, S3><<<dim3(M_ROWS / 64, S3 / 64, NEXP), blk, 0, stream>>>(c2, W3, h);
    lif_scan<S3><<<(BATCH * S3) / 256, blk, 0, stream>>>(h, g3, c1, out + BATCH * (S1 + S2));
}

// Round 2
// 675.334 us; speedup vs baseline: 4.5595x; 4.5595x over previous
//
#include <hip/hip_runtime.h>
#include <hip/hip_bf16.h>
#include <cmath>

#define T_STEPS 16
#define BATCH   512
#define N_IN    3072
#define S1      256
#define S2      256
#define S3      128
#define NEXP    8
#define M_ROWS  (T_STEPS * BATCH)   // 8192
#define M_HALF  (M_ROWS / 2)        // 4096

typedef int v4i __attribute__((ext_vector_type(4)));

// ---------------------------------------------------------------------------
// async global->LDS 16B (wave-uniform LDS base + lane*16 pattern)
// ---------------------------------------------------------------------------
__device__ __forceinline__ void gl2lds16(const char* g, char* l) {
    __builtin_amdgcn_global_load_lds(
        (const __attribute__((address_space(1))) void*)g,
        (__attribute__((address_space(3))) void*)l, 16, 0, 0);
}

// ---------------------------------------------------------------------------
// cast binary fp32 x -> i8 (values 0/1), vectorized float4 -> char4
// ---------------------------------------------------------------------------
__global__ __launch_bounds__(256) void cast_x_i8(
    const float* __restrict__ x, char* __restrict__ xi)
{
    int idx = blockIdx.x * 256 + threadIdx.x;      // over n/4
    float4 v = ((const float4*)x)[idx];
    char4 c;
    c.x = (char)v.x; c.y = (char)v.y; c.z = (char)v.z; c.w = (char)v.w;
    ((char4*)xi)[idx] = c;
}

// ---------------------------------------------------------------------------
// Digitize weights: w -> round(w * 2^32) = sum_l d_l * 256^l, d_l in [-128,127]
// Output layout: Bd[row][k], row = (e*S + n)*4 + limb, row length K.
// One thread per weight.
// ---------------------------------------------------------------------------
__global__ __launch_bounds__(256) void digitize_w(
    const float* __restrict__ W, char* __restrict__ Bd, int K, long long total)
{
    long long t = (long long)blockIdx.x * 256 + threadIdx.x;
    if (t >= total) return;
    long long row = t / K;          // e*S + n
    int k = (int)(t - row * K);
    double w = (double)W[t];
    long long q = llrint(w * 4294967296.0);
    #pragma unroll
    for (int l = 0; l < 4; ++l) {
        int d = (int)((q + 128) & 255) - 128;
        q = (q - d) >> 8;
        Bd[(row * 4 + l) * (long long)K + k] = (char)d;
    }
}

// ---------------------------------------------------------------------------
// i8 MFMA GEMM with exact limb recombination into fp64 h.
// A: (M_HALF x K) i8 row-major.  B: (NB x K) i8 row-major, NB = E*4*S,
//    B-row = e*4*S + n*4 + limb.
// H[e][m][n] fp64 (m in [0, M_HALF)).
// Block 256 thr = 4 waves; tile 128(M) x 128(B-rows); BK = 64 bytes.
// MFMA: v_mfma_i32_16x16x64_i8 (A/B frag: 16 contiguous k-bytes per lane,
// k = (lane>>4)*16 + j, row = lane&15; C/D: col=lane&15, row=(lane>>4)*4+reg).
// ---------------------------------------------------------------------------
template<int K, int S, int SHIFT>
__global__ __launch_bounds__(256) void gemm_i8(
    const char* __restrict__ A, const char* __restrict__ B,
    double* __restrict__ H)
{
    __shared__ __align__(16) char As[128 * 64];
    __shared__ __align__(16) char Bs[128 * 64];

    const int tid  = threadIdx.x;
    const int lane = tid & 63;
    const int wave = tid >> 6;
    const int wm = (wave & 1) * 64;
    const int wn = (wave >> 1) * 64;
    const int r  = lane & 15;
    const int qd = lane >> 4;

    const char* Ag = A + (size_t)(blockIdx.x * 128) * K;
    const char* Bg = B + (size_t)(blockIdx.y * 128) * K;

    v4i acc[4][4];
    #pragma unroll
    for (int i = 0; i < 4; ++i)
        #pragma unroll
        for (int j = 0; j < 4; ++j) acc[i][j] = (v4i){0, 0, 0, 0};

    for (int k0 = 0; k0 < K; k0 += 64) {
        #pragma unroll
        for (int i = 0; i < 2; ++i) {
            int q = tid + i * 256;            // 0..511
            int row = q >> 2;
            int col = (q & 3) * 16;
            gl2lds16(Ag + (size_t)row * K + k0 + col, As + q * 16);
            gl2lds16(Bg + (size_t)row * K + k0 + col, Bs + q * 16);
        }
        __syncthreads();

        v4i af[4], bf[4];
        #pragma unroll
        for (int i = 0; i < 4; ++i)
            af[i] = *(const v4i*)(As + (wm + i * 16 + r) * 64 + qd * 16);
        #pragma unroll
        for (int j = 0; j < 4; ++j)
            bf[j] = *(const v4i*)(Bs + (wn + j * 16 + r) * 64 + qd * 16);

        #pragma unroll
        for (int i = 0; i < 4; ++i)
            #pragma unroll
            for (int j = 0; j < 4; ++j)
                acc[i][j] = __builtin_amdgcn_mfma_i32_16x16x64_i8(
                    af[i], bf[j], acc[i][j], 0, 0, 0);
        __syncthreads();
    }

    // Epilogue: recombine 4 limbs (adjacent C columns) exactly in double.
    const double sbase = 1.0 / (double)(1ll << SHIFT);
    const int col128 = wn + r;                 // + j*16 added per j
    #pragma unroll
    for (int j = 0; j < 4; ++j) {
        int brow = blockIdx.y * 128 + col128 + j * 16;
        int limb = brow & 3;
        int nloc = (brow >> 2) & (S - 1);
        int e    = brow >> (2 + (S == 256 ? 8 : 7));
        double lscale = (double)(1 << (8 * limb)) * sbase;
        #pragma unroll
        for (int i = 0; i < 4; ++i) {
            #pragma unroll
            for (int reg = 0; reg < 4; ++reg) {
                double d = (double)acc[i][j][reg] * lscale;
                d += __shfl_xor(d, 1);
                d += __shfl_xor(d, 2);
                if ((lane & 3) == 0) {
                    int m = blockIdx.x * 128 + wm + i * 16 + qd * 4 + reg;
                    H[((size_t)e * M_HALF + m) * S + nloc] = d;
                }
            }
        }
    }
}

// ---------------------------------------------------------------------------
// LIF scan over one T-half (8 steps). fp64 state, exact spike counting.
// H[e][m][n], m = t_local*BATCH + b. C (i8 counts) row t_global*BATCH+b.
// Vst carries membrane state between halves. Mean partial in f32 (exact).
// ---------------------------------------------------------------------------
template<int S>
__global__ __launch_bounds__(256) void lif_scan_half(
    const double* __restrict__ H, const float* __restrict__ g,
    double* __restrict__ Vst, char* __restrict__ C,
    float* __restrict__ Mean, int half)
{
    const int idx = blockIdx.x * 256 + threadIdx.x;   // b*S + o
    double v[NEXP], gv[NEXP];
    #pragma unroll
    for (int e = 0; e < NEXP; ++e) {
        gv[e] = (double)g[e];
        v[e] = (half == 0) ? 0.0 : Vst[(size_t)e * BATCH * S + idx];
    }
    double acc = 0.0;
    for (int t = 0; t < 8; ++t) {
        int cnt = 0;
        double gs = 0.0;
        #pragma unroll
        for (int e = 0; e < NEXP; ++e) {
            double h = H[(size_t)e * M_HALF * S + (size_t)t * BATCH * S + idx];
            double vv = v[e] * 0.95 + h;
            if (vv >= 1.0) { vv -= 1.0; cnt++; gs += gv[e]; }
            v[e] = vv;
        }
        C[(size_t)(half * 8 + t) * BATCH * S + idx] = (char)cnt;
        acc += gs;
    }
    #pragma unroll
    for (int e = 0; e < NEXP; ++e) Vst[(size_t)e * BATCH * S + idx] = v[e];
    if (half == 0) Mean[idx] = (float)acc;                    // exact (k/8)
    else           Mean[idx] = (Mean[idx] + (float)acc) * 0.0625f;
}

// ---------------------------------------------------------------------------
// ws layout (bytes):
//   h   @ 0          : 64 MB   (E * 4096 * 256 * 8 max, reused per stage/half)
//   v   @ 67108864   :  8 MB   (E * B * 256 * 8, reused per stage)
//   c1  @ 75497472   :  2 MB   (i8 counts, 8192 x 256)
//   c2  @ 77594624   :  2 MB
//   A1  @ 79691776   : 24 MB   (i8 x, 8192 x 3072)
//   B1d @ 104857600  : 24 MB   (8*1024 x 3072 i8 digits)
//   B2d @ 130023424  :  2 MB   (8*1024 x 256)
//   B3d @ 132120576  :  1 MB   (8*512 x 256)
// total ~127 MB
// ---------------------------------------------------------------------------
extern "C" void kernel_launch(void* const* d_in, const int* in_sizes, int n_in,
                              void* d_out, int out_size, void* d_ws, size_t ws_size,
                              hipStream_t stream) {
    const float* x  = (const float*)d_in[0];
    const float* W1 = (const float*)d_in[1];
    const float* W2 = (const float*)d_in[2];
    const float* W3 = (const float*)d_in[3];
    const float* g1 = (const float*)d_in[4];
    const float* g2 = (const float*)d_in[5];
    const float* g3 = (const float*)d_in[6];
    float* out = (float*)d_out;

    char* ws = (char*)d_ws;
    double* h   = (double*)ws;
    double* vst = (double*)(ws + 67108864ull);
    char* c1    = ws + 75497472ull;
    char* c2    = ws + 77594624ull;
    char* A1    = ws + 79691776ull;
    char* B1d   = ws + 104857600ull;
    char* B2d   = ws + 130023424ull;
    char* B3d   = ws + 132120576ull;

    dim3 blk(256);

    // --- precompute: cast x, digitize weights ---
    cast_x_i8<<<(M_ROWS * N_IN / 4) / 256, blk, 0, stream>>>(x, A1);
    digitize_w<<<(NEXP * S1 * N_IN + 255) / 256, blk, 0, stream>>>(
        W1, B1d, N_IN, (long long)NEXP * S1 * N_IN);
    digitize_w<<<(NEXP * S2 * S1 + 255) / 256, blk, 0, stream>>>(
        W2, B2d, S1, (long long)NEXP * S2 * S1);
    digitize_w<<<(NEXP * S3 * S2 + 255) / 256, blk, 0, stream>>>(
        W3, B3d, S2, (long long)NEXP * S3 * S2);

    // --- stage 1: two T-halves of (GEMM -> LIF scan) ---
    for (int half = 0; half < 2; ++half) {
        gemm_i8<N_IN, S1, 32><<<dim3(M_HALF / 128, NEXP * 4 * S1 / 128), blk, 0, stream>>>(
            A1 + (size_t)half * M_HALF * N_IN, B1d, h);
        lif_scan_half<S1><<<(BATCH * S1) / 256, blk, 0, stream>>>(
            h, g1, vst, c1, out, half);
    }
    // --- stage 2 (input counts scaled by g=1/8 via SHIFT=35) ---
    for (int half = 0; half < 2; ++half) {
        gemm_i8<S1, S2, 35><<<dim3(M_HALF / 128, NEXP * 4 * S2 / 128), blk, 0, stream>>>(
            c1 + (size_t)half * M_HALF * S1, B2d, h);
        lif_scan_half<S2><<<(BATCH * S2) / 256, blk, 0, stream>>>(
            h, g2, vst, c2, out + BATCH * S1, half);
    }
    // --- stage 3 ---
    for (int half = 0; half < 2; ++half) {
        gemm_i8<S2, S3, 35><<<dim3(M_HALF / 128, NEXP * 4 * S3 / 128), blk, 0, stream>>>(
            c2 + (size_t)half * M_HALF * S2, B3d, h);
        lif_scan_half<S3><<<(BATCH * S3) / 256, blk, 0, stream>>>(
            h, g3, vst, c1, out + BATCH * (S1 + S2), half);
    }
}

// Round 3
// 632.330 us; speedup vs baseline: 4.8696x; 1.0680x over previous
//
#include <hip/hip_runtime.h>
#include <hip/hip_bf16.h>
#include <cmath>

#define T_STEPS 16
#define BATCH   512
#define N_IN    3072
#define S1      256
#define S2      256
#define S3      128
#define NEXP    8
#define M_ROWS  (T_STEPS * BATCH)   // 8192
#define M_HALF  (M_ROWS / 2)        // 4096

typedef int v4i  __attribute__((ext_vector_type(4)));
typedef int v16i __attribute__((ext_vector_type(16)));

// ---------------------------------------------------------------------------
// async global->LDS 16B (LDS dest = wave-uniform base + lane*16)
// ---------------------------------------------------------------------------
__device__ __forceinline__ void gl2lds16(const char* g, char* l) {
    __builtin_amdgcn_global_load_lds(
        (const __attribute__((address_space(1))) void*)g,
        (__attribute__((address_space(3))) void*)l, 16, 0, 0);
}

// ---------------------------------------------------------------------------
// cast binary fp32 x -> i8 (values 0/1)
// ---------------------------------------------------------------------------
__global__ __launch_bounds__(256) void cast_x_i8(
    const float* __restrict__ x, char* __restrict__ xi)
{
    int idx = blockIdx.x * 256 + threadIdx.x;
    float4 v = ((const float4*)x)[idx];
    char4 c;
    c.x = (char)v.x; c.y = (char)v.y; c.z = (char)v.z; c.w = (char)v.w;
    ((char4*)xi)[idx] = c;
}

// ---------------------------------------------------------------------------
// Digitize weights: w -> round(w*2^32) = sum_l d_l*256^l, d_l in [-128,127].
// One thread per 4 weights (float4 in, one char4 per limb row out, coalesced).
// Bd row = (e*S + n)*4 + limb, length K.
// ---------------------------------------------------------------------------
__global__ __launch_bounds__(256) void digitize_w(
    const float* __restrict__ W, char* __restrict__ Bd, int K, long long total4)
{
    long long t = (long long)blockIdx.x * 256 + threadIdx.x;
    if (t >= total4) return;
    const int kq = K >> 2;
    long long row = t / kq;             // e*S + n
    int kc = (int)(t - row * kq);
    float4 w = ((const float4*)W)[t];
    long long q[4];
    q[0] = llrint((double)w.x * 4294967296.0);
    q[1] = llrint((double)w.y * 4294967296.0);
    q[2] = llrint((double)w.z * 4294967296.0);
    q[3] = llrint((double)w.w * 4294967296.0);
    char* base = Bd + row * 4 * (long long)K + kc * 4;
    #pragma unroll
    for (int l = 0; l < 4; ++l) {
        char4 d;
        int d0 = (int)((q[0] + 128) & 255) - 128; q[0] = (q[0] - d0) >> 8;
        int d1 = (int)((q[1] + 128) & 255) - 128; q[1] = (q[1] - d1) >> 8;
        int d2 = (int)((q[2] + 128) & 255) - 128; q[2] = (q[2] - d2) >> 8;
        int d3 = (int)((q[3] + 128) & 255) - 128; q[3] = (q[3] - d3) >> 8;
        d.x = (char)d0; d.y = (char)d1; d.z = (char)d2; d.w = (char)d3;
        *(char4*)(base + (long long)l * K) = d;
    }
}

// ---------------------------------------------------------------------------
// i8 MFMA GEMM (32x32x32), exact limb recombination into fp64 H.
// A: (M_HALF x K) i8. B: (NB x K) i8, B-row = (e*S+n)*4 + limb.
// H layout: [e][nblk=S/32][m][32] fp64  (aligned 64B epilogue runs).
// Block 256 = 4 waves; tile 128(M) x 128(B-rows) x BK=128.
// LDS rows are 128B, 16B-chunk position XOR-swizzled by (row&7) ->
// conflict-free ds_read_b128 (every 8 consecutive lanes cover all 32 banks).
// Swizzle is applied on the DMA's *global* source address (LDS side must be
// lane-contiguous).
// A-frag: A[m=lane&31][k=(lane>>5)*16+j]; C/D: col=lane&31,
// row=(reg&3)+8*(reg>>2)+4*(lane>>5).
// ---------------------------------------------------------------------------
template<int K, int S, int SHIFT>
__global__ __launch_bounds__(256) void gemm_i8(
    const char* __restrict__ A, const char* __restrict__ B,
    double* __restrict__ H)
{
    __shared__ __align__(16) char As[128 * 128];
    __shared__ __align__(16) char Bs[128 * 128];

    const int tid  = threadIdx.x;
    const int lane = tid & 63;
    const int wave = tid >> 6;
    const int wm  = (wave & 1) * 64;
    const int wn  = (wave >> 1) * 64;
    const int col = lane & 31;
    const int qd  = lane >> 5;

    const char* Ag = A + (size_t)(blockIdx.x * 128) * K;
    const char* Bg = B + (size_t)(blockIdx.y * 128) * K;

    v16i acc[2][2];
    #pragma unroll
    for (int i = 0; i < 2; ++i)
        #pragma unroll
        for (int j = 0; j < 2; ++j)
            #pragma unroll
            for (int r = 0; r < 16; ++r) acc[i][j][r] = 0;

    for (int k0 = 0; k0 < K; k0 += 128) {
        #pragma unroll
        for (int i = 0; i < 4; ++i) {
            int slot = tid + i * 256;          // 0..1023
            int row  = slot >> 3;              // LDS row (128B)
            int ch   = (slot & 7) ^ (row & 7); // logical 16B chunk for this slot
            gl2lds16(Ag + (size_t)row * K + k0 + ch * 16, As + slot * 16);
            gl2lds16(Bg + (size_t)row * K + k0 + ch * 16, Bs + slot * 16);
        }
        __syncthreads();

        #pragma unroll
        for (int ks = 0; ks < 4; ++ks) {
            v4i af[2], bf[2];
            #pragma unroll
            for (int i = 0; i < 2; ++i) {
                int row = wm + i * 32 + col;
                int ch  = (ks * 2 + qd) ^ (row & 7);
                af[i] = *(const v4i*)(As + row * 128 + ch * 16);
            }
            #pragma unroll
            for (int j = 0; j < 2; ++j) {
                int row = wn + j * 32 + col;
                int ch  = (ks * 2 + qd) ^ (row & 7);
                bf[j] = *(const v4i*)(Bs + row * 128 + ch * 16);
            }
            #pragma unroll
            for (int i = 0; i < 2; ++i)
                #pragma unroll
                for (int j = 0; j < 2; ++j)
                    acc[i][j] = __builtin_amdgcn_mfma_i32_32x32x32_i8(
                        af[i], bf[j], acc[i][j], 0, 0, 0);
        }
        __syncthreads();
    }

    // Epilogue: adjacent C cols = 4 limbs of one output; recombine in double.
    const double sbase = 1.0 / (double)(1ll << SHIFT);
    #pragma unroll
    for (int j = 0; j < 2; ++j) {
        int brow  = blockIdx.y * 128 + wn + j * 32 + col;
        int limb  = brow & 3;
        int nglob = brow >> 2;              // e*S + nloc
        int e     = nglob / S;
        int nloc  = nglob % S;
        double lscale = (double)(1 << (8 * limb)) * sbase;
        size_t hb = (((size_t)e * (S / 32) + (nloc >> 5)) * M_HALF) * 32 + (nloc & 31);
        #pragma unroll
        for (int i = 0; i < 2; ++i) {
            #pragma unroll
            for (int reg = 0; reg < 16; ++reg) {
                double d = (double)acc[i][j][reg] * lscale;
                d += __shfl_xor(d, 1);
                d += __shfl_xor(d, 2);
                if ((lane & 3) == 0) {
                    int m = blockIdx.x * 128 + wm + i * 32
                          + (reg & 3) + 8 * (reg >> 2) + 4 * qd;
                    H[hb + (size_t)m * 32] = d;
                }
            }
        }
    }
}

// ---------------------------------------------------------------------------
// LIF scan over one T-half (8 steps). fp64 state, exact spike counting.
// H: [e][nblk][m][32], m = t_local*BATCH + b.
// ---------------------------------------------------------------------------
template<int S>
__global__ __launch_bounds__(256) void lif_scan_half(
    const double* __restrict__ H, const float* __restrict__ g,
    double* __restrict__ Vst, char* __restrict__ C,
    float* __restrict__ Mean, int half)
{
    const int idx = blockIdx.x * 256 + threadIdx.x;   // b*S + o
    const int b = idx / S;
    const int o = idx % S;
    const size_t ns = (size_t)(o >> 5) * M_HALF * 32 + (o & 31);

    double v[NEXP], gv[NEXP];
    #pragma unroll
    for (int e = 0; e < NEXP; ++e) {
        gv[e] = (double)g[e];
        v[e] = (half == 0) ? 0.0 : Vst[(size_t)e * BATCH * S + idx];
    }
    double acc = 0.0;
    for (int t = 0; t < 8; ++t) {
        int cnt = 0;
        double gs = 0.0;
        #pragma unroll
        for (int e = 0; e < NEXP; ++e) {
            double h = H[(size_t)e * (S / 32) * M_HALF * 32 + ns
                         + (size_t)(t * BATCH + b) * 32];
            double vv = v[e] * 0.95 + h;
            if (vv >= 1.0) { vv -= 1.0; cnt++; gs += gv[e]; }
            v[e] = vv;
        }
        C[(size_t)(half * 8 + t) * BATCH * S + idx] = (char)cnt;
        acc += gs;
    }
    #pragma unroll
    for (int e = 0; e < NEXP; ++e) Vst[(size_t)e * BATCH * S + idx] = v[e];
    if (half == 0) Mean[idx] = (float)acc;
    else           Mean[idx] = (Mean[idx] + (float)acc) * 0.0625f;
}

// ---------------------------------------------------------------------------
// ws layout (bytes):
//   h   @ 0          : 64 MB   (E * 4096 * S * 8 max, reused per stage/half)
//   v   @ 67108864   :  8 MB
//   c1  @ 75497472   :  2 MB   (i8 counts)
//   c2  @ 77594624   :  2 MB
//   A1  @ 79691776   : 24 MB   (i8 x)
//   B1d @ 104857600  : 24 MB
//   B2d @ 130023424  :  2 MB
//   B3d @ 132120576  :  1 MB
// ---------------------------------------------------------------------------
extern "C" void kernel_launch(void* const* d_in, const int* in_sizes, int n_in,
                              void* d_out, int out_size, void* d_ws, size_t ws_size,
                              hipStream_t stream) {
    const float* x  = (const float*)d_in[0];
    const float* W1 = (const float*)d_in[1];
    const float* W2 = (const float*)d_in[2];
    const float* W3 = (const float*)d_in[3];
    const float* g1 = (const float*)d_in[4];
    const float* g2 = (const float*)d_in[5];
    const float* g3 = (const float*)d_in[6];
    float* out = (float*)d_out;

    char* ws = (char*)d_ws;
    double* h   = (double*)ws;
    double* vst = (double*)(ws + 67108864ull);
    char* c1    = ws + 75497472ull;
    char* c2    = ws + 77594624ull;
    char* A1    = ws + 79691776ull;
    char* B1d   = ws + 104857600ull;
    char* B2d   = ws + 130023424ull;
    char* B3d   = ws + 132120576ull;

    dim3 blk(256);

    cast_x_i8<<<(M_ROWS * N_IN / 4) / 256, blk, 0, stream>>>(x, A1);
    digitize_w<<<((NEXP * S1 * N_IN / 4) + 255) / 256, blk, 0, stream>>>(
        W1, B1d, N_IN, (long long)NEXP * S1 * N_IN / 4);
    digitize_w<<<((NEXP * S2 * S1 / 4) + 255) / 256, blk, 0, stream>>>(
        W2, B2d, S1, (long long)NEXP * S2 * S1 / 4);
    digitize_w<<<((NEXP * S3 * S2 / 4) + 255) / 256, blk, 0, stream>>>(
        W3, B3d, S2, (long long)NEXP * S3 * S2 / 4);

    // --- stage 1 ---
    for (int half = 0; half < 2; ++half) {
        gemm_i8<N_IN, S1, 32><<<dim3(M_HALF / 128, NEXP * 4 * S1 / 128), blk, 0, stream>>>(
            A1 + (size_t)half * M_HALF * N_IN, B1d, h);
        lif_scan_half<S1><<<(BATCH * S1) / 256, blk, 0, stream>>>(
            h, g1, vst, c1, out, half);
    }
    // --- stage 2 (input counts 0..8; gate 1/8 folded via SHIFT=35) ---
    for (int half = 0; half < 2; ++half) {
        gemm_i8<S1, S2, 35><<<dim3(M_HALF / 128, NEXP * 4 * S2 / 128), blk, 0, stream>>>(
            c1 + (size_t)half * M_HALF * S1, B2d, h);
        lif_scan_half<S2><<<(BATCH * S2) / 256, blk, 0, stream>>>(
            h, g2, vst, c2, out + BATCH * S1, half);
    }
    // --- stage 3 ---
    for (int half = 0; half < 2; ++half) {
        gemm_i8<S2, S3, 35><<<dim3(M_HALF / 128, NEXP * 4 * S3 / 128), blk, 0, stream>>>(
            c2 + (size_t)half * M_HALF * S2, B3d, h);
        lif_scan_half<S3><<<(BATCH * S3) / 256, blk, 0, stream>>>(
            h, g3, vst, c1, out + BATCH * (S1 + S2), half);
    }
}